// Round 8
// baseline (553.623 us; speedup 1.0000x reference)
//
#include <hip/hip_runtime.h>

#define BB 4
#define CC 32
#define HH 128
#define WW 256
#define CR 85
#define EPSF 1e-5f

// Output offsets (elements): out0 @0, out1 @4194304, out2 @8388608, out3 @41943040
#define O1_OFF 4194304
#define O2_OFF 8388608
#define COST1 33554432   // elements per direction of cost / out2-3

typedef __attribute__((ext_vector_type(8))) short bf16x8;
typedef __attribute__((ext_vector_type(4))) float f32x4;
typedef __attribute__((ext_vector_type(4))) float f4v;

static __device__ __forceinline__ unsigned short f2bf(float f) {
    unsigned u = __float_as_uint(f);
    unsigned r = (u + 0x7FFFu + ((u >> 16) & 1u)) >> 16;   // RNE
    return (unsigned short)r;
}

// LDS-only barrier: orders ds ops across the block WITHOUT draining vmcnt,
// so nt cost loads / nt stores stay in flight across it (T4 principle:
// never vmcnt(0) in the loop). All barriers in this kernel exist only to
// order LDS (Sb exchange / weight overlay / Qs,Ks publication); global and
// LDS never alias here, so vmcnt is semantically unneeded at every barrier.
#define LBAR() do { \
    asm volatile("s_waitcnt lgkmcnt(0)" ::: "memory"); \
    __builtin_amdgcn_s_barrier(); \
} while (0)

// ---------------- Fused kernel: projection + 2*x outputs + MFMA scores + cost stream ----
// block = (dir, bh). R4 structure: Q/K for the whole 256-px row projected into
// LDS once, then 8 row-tiles stream cost->out (prefetch-nt -> MFMA -> Sb
// exchange -> band-add -> nt store). LDS 48.5 KB -> 3 blocks/CU.
// R6 delta: lgkm-only barriers (global stream never drained), tile-0 prefetch
// hoisted before projection, next-tile prefetch interleaved into the epilogue.
__global__ __launch_bounds__(256, 3)
void pab_fused_one(const float* __restrict__ x_left, const float* __restrict__ x_right,
                   const float* __restrict__ cost,
                   const float* __restrict__ q_w, const float* __restrict__ q_b,
                   const float* __restrict__ q_gamma, const float* __restrict__ q_beta,
                   const float* __restrict__ q_mean, const float* __restrict__ q_var,
                   const float* __restrict__ k_w, const float* __restrict__ k_b,
                   const float* __restrict__ k_gamma, const float* __restrict__ k_beta,
                   const float* __restrict__ k_mean, const float* __restrict__ k_var,
                   float* __restrict__ out)
{
    __shared__ unsigned short Qs[WW * CC];   // [px][ch] bf16, 16 KB
    __shared__ unsigned short Ks[WW * CC];   // [px][ch] bf16, 16 KB
    __shared__ char smem[32 * 132 * 4];      // 16.9 KB: weights (phase 1) / Sb (phase 2)
    float* Sb = (float*)smem;                          // [32][132] fp32
    float (*wqs)[CC] = (float(*)[CC])smem;             // [c][o], 4 KB
    float (*wks)[CC] = (float(*)[CC])(smem + 4096);    // 4 KB
    float* bqs = (float*)(smem + 8192);                // 128 B
    float* bks = (float*)(smem + 8320);
    float* sqs = (float*)(smem + 8448);
    float* sks = (float*)(smem + 8576);

    const int t   = threadIdx.x;      // px within row
    const int dir = blockIdx.x >> 9;  // 0 = r2l, 1 = l2r
    const int bh  = blockIdx.x & 511;
    const int b = bh >> 7, h = bh & 127;

    const float* csrc = cost + (size_t)dir * COST1 + (size_t)bh * (WW * WW);
    float* odst = out + O2_OFF + (size_t)dir * COST1 + (size_t)bh * (WW * WW);
    const int rowlane = t >> 6;        // 0..3
    const int c4 = 4 * (t & 63);

    // ---- tile-0 cost prefetch: in flight across the whole projection phase ----
    f4v vbuf[8];
    #pragma unroll
    for (int p = 0; p < 8; ++p) {
        int rl = 4 * p + rowlane;
        vbuf[p] = __builtin_nontemporal_load((const f4v*)(csrc + rl * WW + c4));
    }

    // ---- phase 1a: BN fold ----
    if (t < CC) {
        float qs_ = q_gamma[t] * rsqrtf(q_var[t] + EPSF);
        float ks_ = k_gamma[t] * rsqrtf(k_var[t] + EPSF);
        sqs[t] = qs_; sks[t] = ks_;
        bqs[t] = q_b[t] * qs_ + q_beta[t] - q_mean[t] * qs_;
        bks[t] = k_b[t] * ks_ + k_beta[t] - k_mean[t] * ks_;
    }
    LBAR();
    for (int r = t; r < CC * CC; r += 256) {
        int o = r >> 5, c = r & 31;
        wqs[c][o] = q_w[r] * sqs[o];
        wks[c][o] = k_w[r] * sks[o];
    }
    LBAR();

    // ---- phase 1b: project Q (dir's Q side) and K (other side) for the full row ----
    // dir0 (r2l): Q from left, K from right; dir1 (l2r): Q from right, K from left
    const float* xq = dir ? x_right : x_left;
    const float* xk = dir ? x_left  : x_right;
    float* outq = out + (dir ? O1_OFF : 0);     // this dir owns its Q side's 2*x copy
    const int xbase = (b * CC * HH + h) * WW + t;

    {
        float q[CC];
        #pragma unroll
        for (int o = 0; o < CC; ++o) q[o] = bqs[o];
        #pragma unroll 4
        for (int c = 0; c < CC; ++c) {
            int idx = xbase + c * (HH * WW);
            float xv = xq[idx];                               // read 2x total: keep cached
            __builtin_nontemporal_store(2.0f * xv, outq + idx);
            #pragma unroll
            for (int o = 0; o < CC; ++o) q[o] += xv * wqs[c][o];
        }
        unsigned short* qdst = Qs + t * CC;
        #pragma unroll
        for (int g = 0; g < 4; ++g) {
            uint4 v;
            v.x = f2bf(q[8*g+0]) | ((unsigned)f2bf(q[8*g+1]) << 16);
            v.y = f2bf(q[8*g+2]) | ((unsigned)f2bf(q[8*g+3]) << 16);
            v.z = f2bf(q[8*g+4]) | ((unsigned)f2bf(q[8*g+5]) << 16);
            v.w = f2bf(q[8*g+6]) | ((unsigned)f2bf(q[8*g+7]) << 16);
            ((uint4*)qdst)[g] = v;
        }
    }
    {
        float k[CC];
        #pragma unroll
        for (int o = 0; o < CC; ++o) k[o] = bks[o];
        #pragma unroll 4
        for (int c = 0; c < CC; ++c) {
            float xv = xk[xbase + c * (HH * WW)];
            #pragma unroll
            for (int o = 0; o < CC; ++o) k[o] += xv * wks[c][o];
        }
        unsigned short* kdst = Ks + t * CC;
        #pragma unroll
        for (int g = 0; g < 4; ++g) {
            uint4 v;
            v.x = f2bf(k[8*g+0]) | ((unsigned)f2bf(k[8*g+1]) << 16);
            v.y = f2bf(k[8*g+2]) | ((unsigned)f2bf(k[8*g+3]) << 16);
            v.z = f2bf(k[8*g+4]) | ((unsigned)f2bf(k[8*g+5]) << 16);
            v.w = f2bf(k[8*g+6]) | ((unsigned)f2bf(k[8*g+7]) << 16);
            ((uint4*)kdst)[g] = v;
        }
    }
    LBAR();   // Qs/Ks published; weights dead (Sb overwrites after next barrier)

    // ---- phase 2: 8 row-tiles of MFMA + cost stream ----
    const int w = t >> 6, lane = t & 63;
    const int quad = lane >> 4, l16 = lane & 15;
    const float inv32 = 1.0f / 32.0f;

    for (int tile = 0; tile < 8; ++tile) {
        const int i0 = tile * 32;
        const int wbase = dir ? i0 : (i0 - 96);   // window cols [wbase, wbase+128)

        // fragments from LDS-resident row Q/K; OOB window cols -> zero frag
        bf16x8 qf[2], kf[2];
        #pragma unroll
        for (int mt = 0; mt < 2; ++mt)
            qf[mt] = *(const bf16x8*)(Qs + (i0 + 16 * mt + l16) * CC + quad * 8);
        #pragma unroll
        for (int nt = 0; nt < 2; ++nt) {
            int col = wbase + 32 * w + 16 * nt + l16;
            bf16x8 kv = {};
            if (col >= 0 && col < WW)
                kv = *(const bf16x8*)(Ks + col * CC + quad * 8);
            kf[nt] = kv;
        }

        f32x4 acc[2][2] = {};
        #pragma unroll
        for (int mt = 0; mt < 2; ++mt)
            #pragma unroll
            for (int nt = 0; nt < 2; ++nt)
                acc[mt][nt] = __builtin_amdgcn_mfma_f32_16x16x32_bf16(
                    qf[mt], kf[nt], acc[mt][nt], 0, 0, 0);

        LBAR();   // prev tile's Sb reads (and phase-1 weight reads) complete

        // Sb exchange: acc fragment layout -> row-major [32][132]
        #pragma unroll
        for (int mt = 0; mt < 2; ++mt)
            #pragma unroll
            for (int nt = 0; nt < 2; ++nt) {
                int cl = 32 * w + 16 * nt + l16;
                #pragma unroll
                for (int r = 0; r < 4; ++r) {
                    int row = 16 * mt + quad * 4 + r;
                    Sb[row * 132 + cl] = acc[mt][nt][r];
                }
            }
        LBAR();

        // epilogue: band-add into prefetched cost, nt stores; next-tile prefetch
        const int lc = c4 - wbase;
        const bool inwin = (lc >= 0 && lc < 128);
        #pragma unroll
        for (int p = 0; p < 8; ++p) {
            int rl = 4 * p + rowlane;
            int i = i0 + rl;
            f4v v = vbuf[p];
            if (inwin) {
                const f4v s = *(const f4v*)(Sb + rl * 132 + lc);
                int d0 = dir ? (c4 + 0 - i) : (i - c4 - 0);
                int d1 = dir ? (c4 + 1 - i) : (i - c4 - 1);
                int d2 = dir ? (c4 + 2 - i) : (i - c4 - 2);
                int d3 = dir ? (c4 + 3 - i) : (i - c4 - 3);
                if (d0 >= 0 && d0 < CR) v[0] += s[0] * inv32;
                if (d1 >= 0 && d1 < CR) v[1] += s[1] * inv32;
                if (d2 >= 0 && d2 < CR) v[2] += s[2] * inv32;
                if (d3 >= 0 && d3 < CR) v[3] += s[3] * inv32;
            }
            __builtin_nontemporal_store(v, (f4v*)(odst + (size_t)i * WW + c4));
            if (tile < 7)
                vbuf[p] = __builtin_nontemporal_load(
                    (const f4v*)(csrc + (i0 + 32 + rl) * WW + c4));
        }
    }
}

extern "C" void kernel_launch(void* const* d_in, const int* in_sizes, int n_in,
                              void* d_out, int out_size, void* d_ws, size_t ws_size,
                              hipStream_t stream) {
    const float* x_left  = (const float*)d_in[0];
    const float* x_right = (const float*)d_in[1];
    const float* cost    = (const float*)d_in[2];
    const float* q_w     = (const float*)d_in[3];
    const float* q_b     = (const float*)d_in[4];
    const float* q_gamma = (const float*)d_in[5];
    const float* q_beta  = (const float*)d_in[6];
    const float* q_mean  = (const float*)d_in[7];
    const float* q_var   = (const float*)d_in[8];
    const float* k_w     = (const float*)d_in[9];
    const float* k_b     = (const float*)d_in[10];
    const float* k_gamma = (const float*)d_in[11];
    const float* k_beta  = (const float*)d_in[12];
    const float* k_mean  = (const float*)d_in[13];
    const float* k_var   = (const float*)d_in[14];
    float* out = (float*)d_out;

    pab_fused_one<<<dim3(1024), dim3(256), 0, stream>>>(
        x_left, x_right, cost,
        q_w, q_b, q_gamma, q_beta, q_mean, q_var,
        k_w, k_b, k_gamma, k_beta, k_mean, k_var,
        out);
}

// Round 9
// 531.436 us; speedup vs baseline: 1.0417x; 1.0417x over previous
//
#include <hip/hip_runtime.h>

#define BB 4
#define CC 32
#define HH 128
#define WW 256
#define CR 85
#define EPSF 1e-5f

// Output offsets (elements): out0 @0, out1 @4194304, out2 @8388608, out3 @41943040
#define O1_OFF 4194304
#define O2_OFF 8388608
#define COST1 33554432   // elements per direction of cost / out2-3

typedef __attribute__((ext_vector_type(8))) short bf16x8;
typedef __attribute__((ext_vector_type(4))) float f32x4;
typedef __attribute__((ext_vector_type(4))) float f4v;

static __device__ __forceinline__ unsigned short f2bf(float f) {
    unsigned u = __float_as_uint(f);
    unsigned r = (u + 0x7FFFu + ((u >> 16) & 1u)) >> 16;   // RNE
    return (unsigned short)r;
}

// ---------------- Fused kernel: projection + 2*x outputs + MFMA scores + cost stream ----
// block = (dir, bh). No workspace round-trip: Q/K for the whole 256-px row are
// projected into LDS once, then the 8 row-tiles stream cost->out with the proven
// R0 score body (prefetch-nt -> MFMA -> Sb exchange -> band-add -> nt store).
// LDS: Qs 16K + Ks 16K + smem 16.9K (Sb overlaid on BN-folded weights, which are
// dead after the projection phase) = 48.5 KB -> 3 blocks/CU.
// Session-best configuration (531.4 us): plain __syncthreads (the vmcnt drain is
// absorbed by other resident waves' traffic — lgkm-only barriers measured WORSE),
// per-tile batch prefetch (interleaved epilogue prefetch measured worse).
__global__ __launch_bounds__(256, 3)
void pab_fused_one(const float* __restrict__ x_left, const float* __restrict__ x_right,
                   const float* __restrict__ cost,
                   const float* __restrict__ q_w, const float* __restrict__ q_b,
                   const float* __restrict__ q_gamma, const float* __restrict__ q_beta,
                   const float* __restrict__ q_mean, const float* __restrict__ q_var,
                   const float* __restrict__ k_w, const float* __restrict__ k_b,
                   const float* __restrict__ k_gamma, const float* __restrict__ k_beta,
                   const float* __restrict__ k_mean, const float* __restrict__ k_var,
                   float* __restrict__ out)
{
    __shared__ unsigned short Qs[WW * CC];   // [px][ch] bf16, 16 KB
    __shared__ unsigned short Ks[WW * CC];   // [px][ch] bf16, 16 KB
    __shared__ char smem[32 * 132 * 4];      // 16.9 KB: weights (phase 1) / Sb (phase 2)
    float* Sb = (float*)smem;                          // [32][132] fp32
    float (*wqs)[CC] = (float(*)[CC])smem;             // [c][o], 4 KB
    float (*wks)[CC] = (float(*)[CC])(smem + 4096);    // 4 KB
    float* bqs = (float*)(smem + 8192);                // 128 B
    float* bks = (float*)(smem + 8320);
    float* sqs = (float*)(smem + 8448);
    float* sks = (float*)(smem + 8576);

    const int t   = threadIdx.x;      // px within row
    const int dir = blockIdx.x >> 9;  // 0 = r2l, 1 = l2r
    const int bh  = blockIdx.x & 511;
    const int b = bh >> 7, h = bh & 127;

    // ---- phase 1a: BN fold ----
    if (t < CC) {
        float qs_ = q_gamma[t] * rsqrtf(q_var[t] + EPSF);
        float ks_ = k_gamma[t] * rsqrtf(k_var[t] + EPSF);
        sqs[t] = qs_; sks[t] = ks_;
        bqs[t] = q_b[t] * qs_ + q_beta[t] - q_mean[t] * qs_;
        bks[t] = k_b[t] * ks_ + k_beta[t] - k_mean[t] * ks_;
    }
    __syncthreads();
    for (int r = t; r < CC * CC; r += 256) {
        int o = r >> 5, c = r & 31;
        wqs[c][o] = q_w[r] * sqs[o];
        wks[c][o] = k_w[r] * sks[o];
    }
    __syncthreads();

    // ---- phase 1b: project Q (dir's Q side) and K (other side) for the full row ----
    // dir0 (r2l): Q from left, K from right; dir1 (l2r): Q from right, K from left
    const float* xq = dir ? x_right : x_left;
    const float* xk = dir ? x_left  : x_right;
    float* outq = out + (dir ? O1_OFF : 0);     // this dir owns its Q side's 2*x copy
    const int xbase = (b * CC * HH + h) * WW + t;

    {
        float q[CC];
        #pragma unroll
        for (int o = 0; o < CC; ++o) q[o] = bqs[o];
        #pragma unroll 4
        for (int c = 0; c < CC; ++c) {
            int idx = xbase + c * (HH * WW);
            float xv = xq[idx];                               // read 2x total: keep cached
            __builtin_nontemporal_store(2.0f * xv, outq + idx);
            #pragma unroll
            for (int o = 0; o < CC; ++o) q[o] += xv * wqs[c][o];
        }
        unsigned short* qdst = Qs + t * CC;
        #pragma unroll
        for (int g = 0; g < 4; ++g) {
            uint4 v;
            v.x = f2bf(q[8*g+0]) | ((unsigned)f2bf(q[8*g+1]) << 16);
            v.y = f2bf(q[8*g+2]) | ((unsigned)f2bf(q[8*g+3]) << 16);
            v.z = f2bf(q[8*g+4]) | ((unsigned)f2bf(q[8*g+5]) << 16);
            v.w = f2bf(q[8*g+6]) | ((unsigned)f2bf(q[8*g+7]) << 16);
            ((uint4*)qdst)[g] = v;
        }
    }
    {
        float k[CC];
        #pragma unroll
        for (int o = 0; o < CC; ++o) k[o] = bks[o];
        #pragma unroll 4
        for (int c = 0; c < CC; ++c) {
            float xv = xk[xbase + c * (HH * WW)];
            #pragma unroll
            for (int o = 0; o < CC; ++o) k[o] += xv * wks[c][o];
        }
        unsigned short* kdst = Ks + t * CC;
        #pragma unroll
        for (int g = 0; g < 4; ++g) {
            uint4 v;
            v.x = f2bf(k[8*g+0]) | ((unsigned)f2bf(k[8*g+1]) << 16);
            v.y = f2bf(k[8*g+2]) | ((unsigned)f2bf(k[8*g+3]) << 16);
            v.z = f2bf(k[8*g+4]) | ((unsigned)f2bf(k[8*g+5]) << 16);
            v.w = f2bf(k[8*g+6]) | ((unsigned)f2bf(k[8*g+7]) << 16);
            ((uint4*)kdst)[g] = v;
        }
    }
    __syncthreads();   // Qs/Ks ready; weights now dead (Sb may overwrite after next barrier)

    // ---- phase 2: 8 row-tiles of MFMA + cost stream ----
    const float* csrc = cost + (size_t)dir * COST1 + (size_t)bh * (WW * WW);
    float* odst = out + O2_OFF + (size_t)dir * COST1 + (size_t)bh * (WW * WW);
    const int rowlane = t >> 6;        // 0..3
    const int c4 = 4 * (t & 63);
    const int w = t >> 6, lane = t & 63;
    const int quad = lane >> 4, l16 = lane & 15;
    const float inv32 = 1.0f / 32.0f;

    for (int tile = 0; tile < 8; ++tile) {
        const int i0 = tile * 32;
        const int wbase = dir ? i0 : (i0 - 96);   // window cols [wbase, wbase+128)

        // cost prefetch: 8x float4/lane, nt; full-row 1KB/wave coalescing
        f4v vbuf[8];
        #pragma unroll
        for (int p = 0; p < 8; ++p) {
            int rl = 4 * p + rowlane;
            vbuf[p] = __builtin_nontemporal_load((const f4v*)(csrc + (i0 + rl) * WW + c4));
        }

        // fragments from LDS-resident row Q/K; OOB window cols -> zero frag
        bf16x8 qf[2], kf[2];
        #pragma unroll
        for (int mt = 0; mt < 2; ++mt)
            qf[mt] = *(const bf16x8*)(Qs + (i0 + 16 * mt + l16) * CC + quad * 8);
        #pragma unroll
        for (int nt = 0; nt < 2; ++nt) {
            int col = wbase + 32 * w + 16 * nt + l16;
            bf16x8 kv = {};
            if (col >= 0 && col < WW)
                kv = *(const bf16x8*)(Ks + col * CC + quad * 8);
            kf[nt] = kv;
        }

        f32x4 acc[2][2] = {};
        #pragma unroll
        for (int mt = 0; mt < 2; ++mt)
            #pragma unroll
            for (int nt = 0; nt < 2; ++nt)
                acc[mt][nt] = __builtin_amdgcn_mfma_f32_16x16x32_bf16(
                    qf[mt], kf[nt], acc[mt][nt], 0, 0, 0);

        __syncthreads();   // previous tile's Sb reads (and phase-1 weight reads) complete

        // Sb exchange: acc fragment layout -> row-major [32][132]
        #pragma unroll
        for (int mt = 0; mt < 2; ++mt)
            #pragma unroll
            for (int nt = 0; nt < 2; ++nt) {
                int cl = 32 * w + 16 * nt + l16;
                #pragma unroll
                for (int r = 0; r < 4; ++r) {
                    int row = 16 * mt + quad * 4 + r;
                    Sb[row * 132 + cl] = acc[mt][nt][r];
                }
            }
        __syncthreads();

        // epilogue: band-add scores into prefetched cost, nt stores
        const int lc = c4 - wbase;
        const bool inwin = (lc >= 0 && lc < 128);
        #pragma unroll
        for (int p = 0; p < 8; ++p) {
            int rl = 4 * p + rowlane;
            int i = i0 + rl;
            f4v v = vbuf[p];
            if (inwin) {
                const f4v s = *(const f4v*)(Sb + rl * 132 + lc);
                int d0 = dir ? (c4 + 0 - i) : (i - c4 - 0);
                int d1 = dir ? (c4 + 1 - i) : (i - c4 - 1);
                int d2 = dir ? (c4 + 2 - i) : (i - c4 - 2);
                int d3 = dir ? (c4 + 3 - i) : (i - c4 - 3);
                if (d0 >= 0 && d0 < CR) v[0] += s[0] * inv32;
                if (d1 >= 0 && d1 < CR) v[1] += s[1] * inv32;
                if (d2 >= 0 && d2 < CR) v[2] += s[2] * inv32;
                if (d3 >= 0 && d3 < CR) v[3] += s[3] * inv32;
            }
            __builtin_nontemporal_store(v, (f4v*)(odst + (size_t)i * WW + c4));
        }
    }
}

extern "C" void kernel_launch(void* const* d_in, const int* in_sizes, int n_in,
                              void* d_out, int out_size, void* d_ws, size_t ws_size,
                              hipStream_t stream) {
    const float* x_left  = (const float*)d_in[0];
    const float* x_right = (const float*)d_in[1];
    const float* cost    = (const float*)d_in[2];
    const float* q_w     = (const float*)d_in[3];
    const float* q_b     = (const float*)d_in[4];
    const float* q_gamma = (const float*)d_in[5];
    const float* q_beta  = (const float*)d_in[6];
    const float* q_mean  = (const float*)d_in[7];
    const float* q_var   = (const float*)d_in[8];
    const float* k_w     = (const float*)d_in[9];
    const float* k_b     = (const float*)d_in[10];
    const float* k_gamma = (const float*)d_in[11];
    const float* k_beta  = (const float*)d_in[12];
    const float* k_mean  = (const float*)d_in[13];
    const float* k_var   = (const float*)d_in[14];
    float* out = (float*)d_out;

    pab_fused_one<<<dim3(1024), dim3(256), 0, stream>>>(
        x_left, x_right, cost,
        q_w, q_b, q_gamma, q_beta, q_mean, q_var,
        k_w, k_b, k_gamma, k_beta, k_mean, k_var,
        out);
}